// Round 4
// baseline (424.536 us; speedup 1.0000x reference)
//
#include <hip/hip_runtime.h>
#include <hip/hip_bf16.h>

#define N_NODES  50000
#define N_EDGES  800000
#define ND       64
#define ED       32
#define MSGD     128
#define HIDD     256
#define N_AGENTS 25000
#define EPAD     800064   // N_EDGES + 64 (tile padding)

typedef _Float16 f16;
typedef __attribute__((ext_vector_type(4))) _Float16 f16x4;
typedef __attribute__((ext_vector_type(8))) _Float16 f16x8;
typedef __attribute__((ext_vector_type(4))) float f32x4;
typedef unsigned short u16;
typedef unsigned int   u32;
typedef unsigned long long u64;

// Raw workgroup barrier that does NOT drain vmcnt: LDS visibility only.
// (__syncthreads emits s_waitcnt vmcnt(0) lgkmcnt(0) and would serialize the
// in-flight register-staged gathers — the R15 point is to keep them flying.)
// Pattern per learn_hip m201 template (lgkmcnt asm + s_barrier + sched fences).
#define WG_BARRIER() do {                                       \
    __builtin_amdgcn_sched_barrier(0);                          \
    asm volatile("s_waitcnt lgkmcnt(0)" ::: "memory");          \
    __builtin_amdgcn_s_barrier();                               \
    __builtin_amdgcn_sched_barrier(0);                          \
} while (0)

// ============================================================================
// R15: compact + nf->f16 + weight pack fused into ONE kernel (saves a launch).
// Blocks [0, 3125): compact path. Blocks [3125, 3209): pack path.
// Compact keeps only the per-receiver rank atomic (25k addresses, pipelined);
// the dense order is recreated by scatter via off[r]+rank (R14).
// ============================================================================
__global__ __launch_bounds__(256) void compact_pack_kernel(
    const int* __restrict__ recv, const float* __restrict__ nf,
    f16* __restrict__ nf16, int* __restrict__ rankb, int* __restrict__ deg,
    const float* __restrict__ W1, const float* __restrict__ W2,
    const float* __restrict__ Wh1, const float* __restrict__ Wh2,
    f16* __restrict__ F1, f16* __restrict__ F2,
    f16* __restrict__ F3, f16* __restrict__ F4)
{
    int b = blockIdx.x;
    if (b >= N_EDGES / 256) {
        // ---- weight-pack path: frag for 16x16x32:
        // lane l, elem j <-> W[k = ks*32 + (l>>4)*8 + j][n = nt*16 + (l&15)]
        int tid  = (b - N_EDGES / 256) * 256 + threadIdx.x;
        int grp  = tid >> 6, lane = tid & 63;
        const float* W; f16* D; int NT, stride, gl;
        if      (grp < 80)  { W = W1;  D = F1; NT = 16; stride = 256; gl = grp; }
        else if (grp < 144) { W = W2;  D = F2; NT = 8;  stride = 128; gl = grp - 80; }
        else if (grp < 208) { W = Wh1; D = F3; NT = 16; stride = 256; gl = grp - 144; }
        else if (grp < 336) { W = Wh2; D = F4; NT = 16; stride = 256; gl = grp - 208; }
        else return;
        int ks = gl / NT, nt = gl - ks * NT;
        int n  = nt * 16 + (lane & 15);
        int k0 = ks * 32 + (lane >> 4) * 8;
        f16* dst = D + ((size_t)gl * 64 + lane) * 8;
        #pragma unroll
        for (int j = 0; j < 8; ++j)
            dst[j] = (f16)W[(size_t)(k0 + j) * stride + n];
        return;
    }
    int i = b * 256 + threadIdx.x;
    {   // nf -> f16 (coalesced float4 read, f16x4 write)
        float4 v = ((const float4*)nf)[i];
        f16x4 h;
        h.x = (f16)v.x; h.y = (f16)v.y; h.z = (f16)v.z; h.w = (f16)v.w;
        ((f16x4*)nf16)[i] = h;
    }
    int r = recv[i];
    if (r < N_AGENTS)
        rankb[i] = atomicAdd(&deg[r], 1);
}

// ============================================================================
// prefix: exclusive scan deg -> off[25001] (single block)
// ============================================================================
__global__ __launch_bounds__(1024) void prefix_kernel(
    const int* __restrict__ deg, int* __restrict__ off)
{
    __shared__ int part[1024];
    int t = threadIdx.x;
    int i0 = t * 25;
    int s = 0;
    #pragma unroll 1
    for (int i = 0; i < 25; ++i) {
        int idx = i0 + i;
        if (idx < N_AGENTS) s += deg[idx];
    }
    part[t] = s;
    __syncthreads();
    for (int d = 1; d < 1024; d <<= 1) {
        int v = (t >= d) ? part[t - d] : 0;
        __syncthreads();
        part[t] += v;
        __syncthreads();
    }
    int run = (t == 0) ? 0 : part[t - 1];
    #pragma unroll 1
    for (int i = 0; i < 25; ++i) {
        int idx = i0 + i;
        if (idx < N_AGENTS) {
            off[idx] = run;
            run += deg[idx];
        }
    }
    if (t == 1023) off[N_AGENTS] = part[1023];
}

// ============================================================================
// scatter (no atomics): iterate ALL edges; pos = off[recv] + rankb.
// ============================================================================
__global__ __launch_bounds__(256) void scatter_kernel(
    const int* __restrict__ recv, const int* __restrict__ send,
    const int* __restrict__ rankb, const int* __restrict__ off,
    int* __restrict__ eidb, int* __restrict__ sendb, int* __restrict__ recvb)
{
    int i = blockIdx.x * 256 + threadIdx.x;
    int r = recv[i];
    if (r < N_AGENTS) {
        int pos = off[r] + rankb[i];
        eidb[pos]  = i;
        sendb[pos] = send[i];
        recvb[pos] = r;
    }
}

// ============================================================================
// Edge MLP — R15: T14 async-STAGE split + drain-free barriers.
//  - Per-thread staging slots are TILE-INVARIANT (idx = tid): e, g, source
//    pointer, and LDS offset all hoist out of the loop.
//  - Phase A issues gathers for tile t+1 into REGISTERS (no ds_write, no
//    wait) and prefetches indices for t+2 (kills the index->gather chain).
//  - Gathers are written to XF[p^1] only after B2 (~700 cyc window covers
//    L2/L3 and most HBM latency). Compiler emits counted vmcnt before the
//    ds_write (only the 2 index prefetches issued in between).
//  - All 3 barriers are raw s_barrier + lgkmcnt(0): global loads/stores
//    stay in flight across them (no vmcnt(0) drain — the R11-R14 stall).
// Gather addressing per lane is byte-identical to R13/R14 (FETCH 71 MB held;
// R8/R9: do NOT change the per-lane access pattern).
// Grid 512 (measured optimum — R12). XCD-chunked tiles.
// ============================================================================
__global__ __launch_bounds__(512, 4) void edge_mlp_mfma(
    const f16* __restrict__ nf16, const float* __restrict__ ef,
    const f16* __restrict__ F1, const f16* __restrict__ F2,
    const float* __restrict__ b1, const float* __restrict__ b2,
    const float* __restrict__ wg, const float* __restrict__ bg,
    const int* __restrict__ sendb, const int* __restrict__ recvb,
    const int* __restrict__ eidb, const int* __restrict__ cnt,
    f16* __restrict__ msg_out, float* __restrict__ evals)
{
    __shared__ __align__(16) f16 XF[2][5120];       // 20 KB (10 slots x 64 x 8, dbuf)
    __shared__ __align__(16) f16 HB[16][64][8];     // 16 KB
    __shared__ __align__(16) f16 msgt[32][136];     // 8.5 KB
    __shared__ float lpart[8][32];

    const int tid  = threadIdx.x;
    const int wv   = tid >> 6;
    const int lane = tid & 63;
    const int q    = lane >> 4;
    const int li   = lane & 15;
    const int cntv   = cnt[0];
    const int ntiles = (cntv + 31) >> 5;

    // XCD-chunked tile assignment:
    const int xcd   = blockIdx.x & 7;
    const int bslot = blockIdx.x >> 3;
    const int tstep = gridDim.x >> 3;          // blocks per XCD
    const int T8    = (ntiles + 7) >> 3;
    const int tend  = min((xcd + 1) * T8, ntiles);
    const int t0    = xcd * T8 + bslot;

    // ---- tile-invariant staging-slot constants (768 lane-loads / 512 thr) ----
    // slot0: idx = tid (all threads); slot1: idx = tid + 512 (tid < 256 only)
    const int  e_0 = tid / 24,          g_0 = tid - (tid / 24) * 24;
    const int  e_1 = (tid + 512) / 24,  g_1 = (tid + 512) - ((tid + 512) / 24) * 24;
    const bool has1 = (tid < 256);
    const int* ip0 = (g_0 < 8) ? sendb : (g_0 < 16 ? recvb : eidb);
    const int* ip1 = (g_1 < 8) ? sendb : (g_1 < 16 ? recvb : eidb);
    auto lds_off = [](int e, int g) -> int {
        if (g < 16)   // node f16x8: k = g*8 + j
            return (((e >> 4) * 5 + (g >> 2)) * 64 + (e & 15) + 16 * (g & 3)) * 8;
        int k0 = 128 + (g - 16) * 4;   // ef float4: k = k0..k0+3
        return (((e >> 4) * 5 + 4) * 64 + (e & 15) + 16 * ((k0 & 31) >> 3)) * 8 + (k0 & 7);
    };
    const int lo0 = lds_off(e_0, g_0);
    const int lo1 = lds_off(e_1, g_1);
    auto gslot = [&](int g, int i) -> uint4 {
        return (g < 16)
            ? *(const uint4*)(nf16 + (size_t)i * 64 + (g & 7) * 8)
            : *(const uint4*)(ef + (size_t)i * 32 + (g - 16) * 4);
    };
    auto wslot = [&](f16* xb, int lo, int g, uint4 s) {
        if (g < 16) {
            *(uint4*)(xb + lo) = s;
        } else {
            union { uint4 u; float4 f; } cv; cv.u = s;
            f16x4 h;
            h.x = (f16)cv.f.x; h.y = (f16)cv.f.y;
            h.z = (f16)cv.f.z; h.w = (f16)cv.f.w;
            *(f16x4*)(xb + lo) = h;
        }
    };

    // stationary weight fragments: W1 2 col-tiles + W2 1 col-tile per wave
    f16x8 w1[2][5], w2[8];
    #pragma unroll
    for (int ntl = 0; ntl < 2; ++ntl)
        #pragma unroll
        for (int ks = 0; ks < 5; ++ks)
            w1[ntl][ks] = *(const f16x8*)(F1 + (((size_t)(ks * 16 + 2 * wv + ntl)) * 64 + lane) * 8);
    #pragma unroll
    for (int ks = 0; ks < 8; ++ks)
        w2[ks] = *(const f16x8*)(F2 + (((size_t)(ks * 8 + wv)) * 64 + lane) * 8);

    const float4 ba  = *(const float4*)&b1[wv * 32 + q * 4];
    const float4 bb  = *(const float4*)&b1[wv * 32 + 16 + q * 4];
    const float4 bc  = *(const float4*)&b2[wv * 16 + q * 4];
    const float4 wg4 = *(const float4*)&wg[wv * 16 + q * 4];
    const float  bgv = bg[0];

    // ---- prologue: stage tile t0 directly; prefetch indices for t0+tstep ----
    int i0 = 0, i1 = 0;
    if (t0 < tend) {
        int j0i = ip0[t0 * 32 + e_0];
        wslot(XF[0], lo0, g_0, gslot(g_0, j0i));
        if (has1) {
            int j1i = ip1[t0 * 32 + e_1];
            wslot(XF[0], lo1, g_1, gslot(g_1, j1i));
        }
        if (t0 + tstep < tend) {
            i0 = ip0[(t0 + tstep) * 32 + e_0];
            if (has1) i1 = ip1[(t0 + tstep) * 32 + e_1];
        }
    }
    __syncthreads();

    int p = 0;
    for (int t = t0; t < tend; t += tstep) {
        const int e0  = t * 32;
        const int tn  = t + tstep;
        const int tnn = tn + tstep;

        // ---- phase A: issue gathers for tn into regs; prefetch tnn indices ----
        uint4 s0{}, s1{};
        if (tn < tend) {
            s0 = gslot(g_0, i0);
            if (has1) s1 = gslot(g_1, i1);
        }
        int ni0 = 0, ni1 = 0;
        if (tnn < tend) {
            ni0 = ip0[tnn * 32 + e_0];
            if (has1) ni1 = ip1[tnn * 32 + e_1];
        }

        // ---- layer 1: h[col][edge] = W1^T x^T (from XF[p]) ----
        f32x4 acc[2][2];   // [eh][ntl]
        acc[0][0] = f32x4{ba.x, ba.y, ba.z, ba.w}; acc[1][0] = acc[0][0];
        acc[0][1] = f32x4{bb.x, bb.y, bb.z, bb.w}; acc[1][1] = acc[0][1];
        #pragma unroll
        for (int ks = 0; ks < 5; ++ks)
            #pragma unroll
            for (int eh = 0; eh < 2; ++eh) {
                f16x8 xh = *(const f16x8*)&XF[p][((eh * 5 + ks) * 64 + lane) * 8];
                acc[eh][0] = __builtin_amdgcn_mfma_f32_16x16x32_f16(w1[0][ks], xh, acc[eh][0], 0, 0, 0);
                acc[eh][1] = __builtin_amdgcn_mfma_f32_16x16x32_f16(w1[1][ks], xh, acc[eh][1], 0, 0, 0);
            }
        // relu + stash h as layer-2 B frags
        #pragma unroll
        for (int eh = 0; eh < 2; ++eh)
            #pragma unroll
            for (int ntl = 0; ntl < 2; ++ntl) {
                f16x4 hv;
                hv.x = (f16)fmaxf(acc[eh][ntl][0], 0.f);
                hv.y = (f16)fmaxf(acc[eh][ntl][1], 0.f);
                hv.z = (f16)fmaxf(acc[eh][ntl][2], 0.f);
                hv.w = (f16)fmaxf(acc[eh][ntl][3], 0.f);
                int l2 = li + 16 * (2 * ntl + (q >> 1));
                int j0 = (q & 1) * 4;
                *(f16x4*)&HB[eh * 8 + wv][l2][j0] = hv;
            }
        WG_BARRIER();   // B1: HB ready (lgkm only — gathers stay in flight)

        // ---- layer 2: msg[col][edge] = W2^T h^T ----
        f32x4 acc2[2];
        acc2[0] = f32x4{bc.x, bc.y, bc.z, bc.w}; acc2[1] = acc2[0];
        #pragma unroll
        for (int ks2 = 0; ks2 < 8; ++ks2)
            #pragma unroll
            for (int eh = 0; eh < 2; ++eh) {
                f16x8 hh = *(const f16x8*)HB[eh * 8 + ks2][lane];
                acc2[eh] = __builtin_amdgcn_mfma_f32_16x16x32_f16(w2[ks2], hh, acc2[eh], 0, 0, 0);
            }
        // relu + gate partial + msg stash
        {
            float pr[2];
            #pragma unroll
            for (int eh = 0; eh < 2; ++eh) {
                float v0 = fmaxf(acc2[eh][0], 0.f);
                float v1 = fmaxf(acc2[eh][1], 0.f);
                float v2 = fmaxf(acc2[eh][2], 0.f);
                float v3 = fmaxf(acc2[eh][3], 0.f);
                f16x4 mm;
                mm.x = (f16)v0; mm.y = (f16)v1; mm.z = (f16)v2; mm.w = (f16)v3;
                *(f16x4*)&msgt[eh * 16 + li][wv * 16 + q * 4] = mm;
                float pp = v0 * wg4.x + v1 * wg4.y + v2 * wg4.z + v3 * wg4.w;
                pp += __shfl_xor(pp, 16, 64);
                pp += __shfl_xor(pp, 32, 64);
                pr[eh] = pp;
            }
            if (lane < 16) {
                lpart[wv][li]      = pr[0];
                lpart[wv][16 + li] = pr[1];
            }
        }
        WG_BARRIER();   // B2: msgt/lpart ready

        // ---- write staged gathers into XF[p^1] (counted vmcnt: only the 2
        //      index prefetches were issued after them) ----
        if (tn < tend) {
            f16* xb = XF[p ^ 1];
            wslot(xb, lo0, g_0, s0);
            if (has1) wslot(xb, lo1, g_1, s1);
        }

        // ---- writeback: coalesced msg rows + evals = exp(logit) ----
        {
            int row = tid >> 4, cg = tid & 15;
            *(uint4*)(msg_out + (size_t)(e0 + row) * 128 + cg * 8) =
                *(const uint4*)&msgt[row][cg * 8];
        }
        if (tid < 32) {
            float s2 = bgv;
            #pragma unroll
            for (int w = 0; w < 8; ++w) s2 += lpart[w][tid];
            evals[e0 + tid] = expf(s2);   // softmax shift-invariant; |logit|~O(5)
        }

        i0 = ni0; i1 = ni1;
        WG_BARRIER();   // B3: XF[p^1] ready for next layer1
        p ^= 1;
    }
}

// ============================================================================
// Fused CSR softmax-aggregation + agent MLP. 1024 thr, 32 receivers/block.
// Aggregation: 32 threads per receiver, 4 cols each (8 B/lane), sequential
// bucket rows, 4-way software-pipelined (R13).
// ============================================================================
__global__ __launch_bounds__(1024, 4) void agg_agent_mfma(
    const int* __restrict__ off, const float* __restrict__ evals,
    const f16* __restrict__ msg,
    const f16* __restrict__ F3, const f16* __restrict__ F4,
    const float* __restrict__ bh1, const float* __restrict__ bh2,
    const float* __restrict__ Wout, const float* __restrict__ bout,
    float* __restrict__ out)
{
    __shared__ __align__(16) f16 XA[8][64][8];     // 8 KB
    __shared__ __align__(16) f16 HB2[16][64][8];   // 16 KB
    __shared__ float lpart[16][32];

    const int tid  = threadIdx.x;
    const int wv   = tid >> 6;
    const int lane = tid & 63;
    const int q    = lane >> 4;
    const int li   = lane & 15;
    const int a0i  = blockIdx.x * 32;

    // ---- aggregation straight into XA fragment layout ----
    {
        int g = tid >> 5, c = tid & 31;   // receiver a0i+g, cols [c*4, c*4+4)
        int r = a0i + g;
        float den = 1e-9f;
        float4 acc = make_float4(0.f, 0.f, 0.f, 0.f);
        if (r < N_AGENTS) {
            int beg = off[r], end = off[r + 1];
            const u64* mp = (const u64*)(msg + (size_t)beg * 128) + c;
            int pp = beg;
            for (; pp + 3 < end; pp += 4, mp += 128) {
                float e0 = evals[pp], e1 = evals[pp + 1];
                float e2 = evals[pp + 2], e3 = evals[pp + 3];
                u64 u0 = mp[0], u1 = mp[32], u2 = mp[64], u3 = mp[96];
                den += (e0 + e1) + (e2 + e3);
                union { u64 u; f16 h[4]; } c0, c1, c2, c3;
                c0.u = u0; c1.u = u1; c2.u = u2; c3.u = u3;
                acc.x = fmaf(e3, (float)c3.h[0], fmaf(e2, (float)c2.h[0],
                        fmaf(e1, (float)c1.h[0], fmaf(e0, (float)c0.h[0], acc.x))));
                acc.y = fmaf(e3, (float)c3.h[1], fmaf(e2, (float)c2.h[1],
                        fmaf(e1, (float)c1.h[1], fmaf(e0, (float)c0.h[1], acc.y))));
                acc.z = fmaf(e3, (float)c3.h[2], fmaf(e2, (float)c2.h[2],
                        fmaf(e1, (float)c1.h[2], fmaf(e0, (float)c0.h[2], acc.z))));
                acc.w = fmaf(e3, (float)c3.h[3], fmaf(e2, (float)c2.h[3],
                        fmaf(e1, (float)c1.h[3], fmaf(e0, (float)c0.h[3], acc.w))));
            }
            for (; pp < end; ++pp, mp += 32) {
                float e = evals[pp];
                den += e;
                union { u64 u; f16 h[4]; } cv; cv.u = *mp;
                acc.x = fmaf(e, (float)cv.h[0], acc.x);
                acc.y = fmaf(e, (float)cv.h[1], acc.y);
                acc.z = fmaf(e, (float)cv.h[2], acc.z);
                acc.w = fmaf(e, (float)cv.h[3], acc.w);
            }
        }
        float inv = 1.0f / den;
        int k0   = c * 4;
        int slot = (g >> 4) * 4 + (k0 >> 5);
        int ln   = (g & 15) + 16 * ((k0 & 31) >> 3);
        int j0   = k0 & 7;
        f16x4 h;
        h.x = (f16)(acc.x * inv); h.y = (f16)(acc.y * inv);
        h.z = (f16)(acc.z * inv); h.w = (f16)(acc.w * inv);
        *(f16x4*)&XA[slot][ln][j0] = h;
    }
    __syncthreads();

    // ---- weight fragments + layer 1 ----
    f16x8 wh1[4], wh2[8];
    #pragma unroll
    for (int ks = 0; ks < 4; ++ks)
        wh1[ks] = *(const f16x8*)(F3 + (((size_t)(ks * 16 + wv)) * 64 + lane) * 8);
    #pragma unroll
    for (int ks = 0; ks < 8; ++ks)
        wh2[ks] = *(const f16x8*)(F4 + (((size_t)(ks * 16 + wv)) * 64 + lane) * 8);

    f32x4 acc[2] = {};
    #pragma unroll
    for (int ks = 0; ks < 4; ++ks)
        #pragma unroll
        for (int eh = 0; eh < 2; ++eh) {
            f16x8 xh = *(const f16x8*)XA[eh * 4 + ks][lane];
            acc[eh] = __builtin_amdgcn_mfma_f32_16x16x32_f16(wh1[ks], xh, acc[eh], 0, 0, 0);
        }
    {
        const float4 b1v = ((const float4*)bh1)[wv * 4 + q];
        #pragma unroll
        for (int eh = 0; eh < 2; ++eh) {
            f16x4 hv;
            hv.x = (f16)fmaxf(acc[eh][0] + b1v.x, 0.f);
            hv.y = (f16)fmaxf(acc[eh][1] + b1v.y, 0.f);
            hv.z = (f16)fmaxf(acc[eh][2] + b1v.z, 0.f);
            hv.w = (f16)fmaxf(acc[eh][3] + b1v.w, 0.f);
            int l2 = li + 16 * ((wv & 1) * 2 + (q >> 1));
            int j0 = (q & 1) * 4;
            *(f16x4*)&HB2[eh * 8 + (wv >> 1)][l2][j0] = hv;
        }
    }
    __syncthreads();

    // ---- layer 2 + output partial ----
    f32x4 acc2[2] = {};
    #pragma unroll
    for (int ks2 = 0; ks2 < 8; ++ks2)
        #pragma unroll
        for (int eh = 0; eh < 2; ++eh) {
            f16x8 hh = *(const f16x8*)HB2[eh * 8 + ks2][lane];
            acc2[eh] = __builtin_amdgcn_mfma_f32_16x16x32_f16(wh2[ks2], hh, acc2[eh], 0, 0, 0);
        }
    {
        const float4 b2v = ((const float4*)bh2)[wv * 4 + q];
        const float4 wo4 = ((const float4*)Wout)[wv * 4 + q];
        float pr[2];
        #pragma unroll
        for (int eh = 0; eh < 2; ++eh) {
            float pp = fmaxf(acc2[eh][0] + b2v.x, 0.f) * wo4.x
                     + fmaxf(acc2[eh][1] + b2v.y, 0.f) * wo4.y
                     + fmaxf(acc2[eh][2] + b2v.z, 0.f) * wo4.z
                     + fmaxf(acc2[eh][3] + b2v.w, 0.f) * wo4.w;
            pp += __shfl_xor(pp, 16, 64);
            pp += __shfl_xor(pp, 32, 64);
            pr[eh] = pp;
        }
        if (lane < 16) {
            lpart[wv][li]      = pr[0];
            lpart[wv][16 + li] = pr[1];
        }
    }
    __syncthreads();

    if (tid < 32 && a0i + tid < N_AGENTS) {
        float s = bout[0];
        #pragma unroll
        for (int w = 0; w < 16; ++w) s += lpart[w][tid];
        out[a0i + tid] = tanhf(s);
    }
}

// ============================================================================
extern "C" void kernel_launch(void* const* d_in, const int* in_sizes, int n_in,
                              void* d_out, int out_size, void* d_ws, size_t ws_size,
                              hipStream_t stream)
{
    const float* nf   = (const float*)d_in[0];
    const float* ef   = (const float*)d_in[1];
    const float* W1   = (const float*)d_in[2];
    const float* b1   = (const float*)d_in[3];
    const float* W2   = (const float*)d_in[4];
    const float* b2   = (const float*)d_in[5];
    const float* wg   = (const float*)d_in[6];
    const float* bg   = (const float*)d_in[7];
    const float* Wh1  = (const float*)d_in[8];
    const float* bh1  = (const float*)d_in[9];
    const float* Wh2  = (const float*)d_in[10];
    const float* bh2  = (const float*)d_in[11];
    const float* Wout = (const float*)d_in[12];
    const float* bout = (const float*)d_in[13];
    const int*   send = (const int*)d_in[14];
    const int*   recv = (const int*)d_in[15];

    // workspace: [deg|eidb|sendb|recvb] zeroed (tail indices of the last
    // padded tile must gather row 0, not garbage), then the rest
    char* ws = (char*)d_ws;
    int* deg    = (int*)ws;            ws += (size_t)N_AGENTS * 4;
    int* eidb   = (int*)ws;            ws += (size_t)EPAD * 4;
    int* sendb  = (int*)ws;            ws += (size_t)EPAD * 4;
    int* recvb  = (int*)ws;            ws += (size_t)EPAD * 4;
    size_t zero_bytes = (size_t)(ws - (char*)d_ws);
    int* rankb  = (int*)ws;            ws += (size_t)N_EDGES * 4;
    int* off    = (int*)ws;            ws += (size_t)(N_AGENTS + 8) * 4;
    float* evals = (float*)ws;         ws += (size_t)EPAD * 4;
    f16* nf16   = (f16*)ws;            ws += (size_t)N_NODES * ND * 2;
    f16* F1     = (f16*)ws;            ws += (size_t)160 * 256 * 2;
    f16* F2     = (f16*)ws;            ws += (size_t)256 * 128 * 2;
    f16* F3     = (f16*)ws;            ws += (size_t)128 * 256 * 2;
    f16* F4     = (f16*)ws;            ws += (size_t)256 * 256 * 2;
    f16* msg    = (f16*)ws;

    hipMemsetAsync(d_ws, 0, zero_bytes, stream);

    compact_pack_kernel<<<N_EDGES / 256 + 84, 256, 0, stream>>>(
        recv, nf, nf16, rankb, deg, W1, W2, Wh1, Wh2, F1, F2, F3, F4);
    prefix_kernel<<<1, 1024, 0, stream>>>(deg, off);
    scatter_kernel<<<N_EDGES / 256, 256, 0, stream>>>(
        recv, send, rankb, off, eidb, sendb, recvb);
    edge_mlp_mfma<<<512, 512, 0, stream>>>(
        nf16, ef, F1, F2, b1, b2, wg, bg, sendb, recvb, eidb, off + N_AGENTS, msg, evals);
    agg_agent_mfma<<<(N_AGENTS + 31) / 32, 1024, 0, stream>>>(
        off, evals, msg, F3, F4, bh1, bh2, Wout, bout, (float*)d_out);
}